// Round 7
// baseline (639.500 us; speedup 1.0000x reference)
//
#include <hip/hip_runtime.h>
#include <math.h>

#define NP 50000
#define CH 64
#define KMAX 64
#define KNN 16
#define NB 25
#define PTS (NP / NB)            // 2000
#define EPSF 1e-16f
#define NTILES (NP / 16)         // 3125 (16-node tiles for qkv)
#define OCTS (NP / 8)            // 6250 (8-node octets for attn)
#define L2E 1.4426950408889634f
#define LN2 0.6931471805599453f
#define PPB 8                    // pool partials per cloud
#define PROWS (PTS / PPB)        // 250

typedef __attribute__((ext_vector_type(8))) short short8;
typedef __attribute__((ext_vector_type(4))) float float4v;
typedef __attribute__((ext_vector_type(4))) unsigned int uint4v;
typedef __attribute__((ext_vector_type(2))) unsigned int uint2v;
typedef __attribute__((ext_vector_type(4))) unsigned short ushort4v;

__device__ __forceinline__ ushort f2b(float f) {
  unsigned u = __float_as_uint(f);
  unsigned r = (u + 0x7FFFu + ((u >> 16) & 1u)) >> 16;
  return (ushort)r;
}
__device__ __forceinline__ float b2f(ushort h) {
  return __uint_as_float(((unsigned)h) << 16);
}

// ws layout (bytes):
//   qbf  : 3 * NP * CH * 2   (bf16, log2e-scaled Q)
//   kvp  : 3 * NP * CH * 4   (packed dword: K_s bf16 hi | V bf16 lo)
//   x_bf : NP * CH * 2
//   wpack: 36864 ushort (A-frag layout; Q,K pre-scaled by log2e)
//   poolP: NB * PPB * CH fp32 (per-cloud pool partials)
#define QBF_BYTES   ((size_t)3 * NP * CH * 2)
#define KVP_BYTES   ((size_t)3 * NP * CH * 4)
#define XBF_BYTES   ((size_t)NP * CH * 2)
#define WPACK_ELEMS (9 * 4 * 2 * 64 * 8)
#define XV (NP * CH / 4)

// ---------------------------------------------------------------------------
// Kernel 0: prep = pool partials (blocks 0..NB*PPB-1) + x->bf16 + W pack.
// ---------------------------------------------------------------------------
__global__ __launch_bounds__(256) void prep_kernel(
    const float* __restrict__ x,
    const float* __restrict__ Wv,
    const float* __restrict__ Wq,
    const float* __restrict__ Wk,
    ushort* __restrict__ x_bf,
    ushort* __restrict__ wpack,
    float* __restrict__ poolP) {
  const int tid = threadIdx.x;
  const int bid = blockIdx.x;
  __shared__ float red[4][CH];

  if (bid < NB * PPB) {                 // ---- pool partial path ----
    const int lane = tid & 63;
    const int wave = tid >> 6;
    const int cloud = bid >> 3;
    const int part  = bid & 7;
    const float* xb = x + ((size_t)cloud * PTS + part * PROWS) * CH;
    float m0 = -INFINITY, m1 = -INFINITY;
    for (int r = wave * 2; r < PROWS; r += 8) {
      m0 = fmaxf(m0, xb[(size_t)(r + 0) * CH + lane]);
      m1 = fmaxf(m1, xb[(size_t)(r + 1) * CH + lane]);
    }
    red[wave][lane] = fmaxf(m0, m1);
    __syncthreads();
    if (wave == 0) {
      poolP[(size_t)bid * CH + lane] = fmaxf(fmaxf(red[0][lane], red[1][lane]),
                                             fmaxf(red[2][lane], red[3][lane]));
    }
  } else {                              // ---- convert / pack path ----
    const int gid = (bid - NB * PPB) * 256 + tid;
    if (gid < XV) {
      const float4* xv = (const float4*)x;
      float4 v = xv[gid];
      ushort4v o;
      o[0] = f2b(v.x); o[1] = f2b(v.y); o[2] = f2b(v.z); o[3] = f2b(v.w);
      *(ushort4v*)(x_bf + (size_t)gid * 4) = o;
    } else {
      int pid = gid - XV;
      if (pid < WPACK_ELEMS) {
        int j     = pid & 7;
        int lane  = (pid >> 3) & 63;
        int kstep = (pid >> 9) & 1;
        int mtile = (pid >> 10) & 3;
        int mat   = pid >> 12;
        const float* W;
        int d;
        float scale;
        if (mat < 3)      { W = Wq; d = mat;     scale = L2E; }
        else if (mat < 6) { W = Wk; d = mat - 3; scale = L2E; }
        else              { W = Wv; d = mat - 6; scale = 1.f; }
        int oc = mtile * 16 + (lane & 15);
        int ic = kstep * 32 + ((lane >> 4) & 3) * 8 + j;
        wpack[pid] = f2b(W[d * CH * CH + ic * CH + oc] * scale);
      }
    }
  }
}

// ---------------------------------------------------------------------------
// Kernel 1: projections via MFMA 16x16x32 bf16 (A=W^T, B=x^T). 1 tile/wave.
// grid.y: 0..2 = Q_dd (8 A-frags), 3..5 = KV_dd packed (16 A-frags).
// D lane: node=lane&15, oc=mt*16+(lane>>4)*4+reg.
// ---------------------------------------------------------------------------
__global__ __launch_bounds__(256) void qkv_mfma(
    const ushort* __restrict__ x_bf,
    const ushort* __restrict__ wpack,
    ushort* __restrict__ qbf,
    unsigned int* __restrict__ kvp) {
  const int lane = threadIdx.x;
  const int tile = blockIdx.x * 4 + threadIdx.y;
  if (tile >= NTILES) return;
  const int y = blockIdx.y;
  const int kbase = (lane >> 4) * 8;
  const int myNode = tile * 16 + (lane & 15);
  const ushort* xr = x_bf + (size_t)myNode * CH;
  short8 b0 = *(const short8*)(xr + kbase);
  short8 b1 = *(const short8*)(xr + 32 + kbase);

  if (y < 3) {                             // ---- Q slice ----
    const int dd = y;
    ushort* outQ = qbf + (size_t)dd * NP * CH;
#pragma unroll
    for (int mt = 0; mt < 4; ++mt) {
      short8 a0 = *(const short8*)(wpack +
          ((((size_t)dd * 4 + mt) * 2 + 0) * 64 + lane) * 8);
      short8 a1 = *(const short8*)(wpack +
          ((((size_t)dd * 4 + mt) * 2 + 1) * 64 + lane) * 8);
      float4v acc = {0.f, 0.f, 0.f, 0.f};
      acc = __builtin_amdgcn_mfma_f32_16x16x32_bf16(a0, b0, acc, 0, 0, 0);
      acc = __builtin_amdgcn_mfma_f32_16x16x32_bf16(a1, b1, acc, 0, 0, 0);
      int oc = mt * 16 + (lane >> 4) * 4;
      uint2v o;
      o[0] = (unsigned)f2b(acc[0]) | ((unsigned)f2b(acc[1]) << 16);
      o[1] = (unsigned)f2b(acc[2]) | ((unsigned)f2b(acc[3]) << 16);
      *(uint2v*)(outQ + (size_t)myNode * CH + oc) = o;
    }
  } else {                                 // ---- KV packed slice ----
    const int dd = y - 3;
    unsigned int* outKV = kvp + (size_t)dd * NP * CH;
#pragma unroll
    for (int mt = 0; mt < 4; ++mt) {
      short8 k0 = *(const short8*)(wpack +
          ((((size_t)(3 + dd) * 4 + mt) * 2 + 0) * 64 + lane) * 8);
      short8 k1 = *(const short8*)(wpack +
          ((((size_t)(3 + dd) * 4 + mt) * 2 + 1) * 64 + lane) * 8);
      short8 v0 = *(const short8*)(wpack +
          ((((size_t)(6 + dd) * 4 + mt) * 2 + 0) * 64 + lane) * 8);
      short8 v1 = *(const short8*)(wpack +
          ((((size_t)(6 + dd) * 4 + mt) * 2 + 1) * 64 + lane) * 8);
      float4v aK = {0.f, 0.f, 0.f, 0.f};
      float4v aV = {0.f, 0.f, 0.f, 0.f};
      aK = __builtin_amdgcn_mfma_f32_16x16x32_bf16(k0, b0, aK, 0, 0, 0);
      aK = __builtin_amdgcn_mfma_f32_16x16x32_bf16(k1, b1, aK, 0, 0, 0);
      aV = __builtin_amdgcn_mfma_f32_16x16x32_bf16(v0, b0, aV, 0, 0, 0);
      aV = __builtin_amdgcn_mfma_f32_16x16x32_bf16(v1, b1, aV, 0, 0, 0);
      int oc = mt * 16 + (lane >> 4) * 4;
      uint4v o;
#pragma unroll
      for (int i = 0; i < 4; ++i)
        o[i] = ((unsigned)f2b(aK[i]) << 16) | (unsigned)f2b(aV[i]);
      *(uint4v*)(outKV + (size_t)myNode * CH + oc) = o;
    }
  }
}

// ---------------------------------------------------------------------------
// Kernel 2: fused attention. Block = (64,6): 8 nodes; wave wy = (dd, half)
// processes TWO independent node groups A (0-3) and B (4-7) interleaved
// (2 dependence streams, setup amortized 2x). Partials {s, P=accv-q*s} via
// padded LDS; waves 0/1 do the combine for nodes A/B in parallel.
// K is used unmasked from the packed dword (error ~ bf16 ulp).
// ---------------------------------------------------------------------------
__global__ __launch_bounds__(384, 6) void attn_kernel(
    const float* __restrict__ x,
    const float* __restrict__ pos,
    const float* __restrict__ Wp,
    const float* __restrict__ bp,
    const int*   __restrict__ edge_src,
    const ushort* __restrict__ qbf,
    const unsigned int* __restrict__ kvp,
    const float* __restrict__ poolP,
    float* __restrict__ out) {
  const int bx  = blockIdx.x;
  const int xcd = bx & 7;
  const int kk  = bx >> 3;
  const int base = (OCTS * xcd) >> 3;
  const int cnt  = ((OCTS * (xcd + 1)) >> 3) - base;
  if (kk >= cnt) return;                    // whole-block uniform
  const int node0 = (base + kk) * 8;

  const int wy   = threadIdx.y;             // 0..5
  const int dd   = wy % 3;                  // wave-uniform dilation
  const int half = wy / 3;                  // 0 or 1 (edge half)
  const int tid  = wy * 64 + threadIdx.x;

  __shared__ float sEdge[8 * 260];          // [nl][p] {relx,rely,relz,rowOfs}
  __shared__ float sS[6 * 8 * 68];          // [wy][nl][ch] partial s
  __shared__ float sP[6 * 8 * 68];          // [wy][nl][ch] partial accv-q*s

  for (int r = tid; r < 8 * KMAX; r += 384) {
    int nl = r >> 6, p = r & 63;
    int nd = node0 + nl;
    int j = edge_src[(size_t)nd * KMAX + p];
    float4v w;
    w[0] = pos[nd * 3 + 0] - pos[j * 3 + 0];
    w[1] = pos[nd * 3 + 1] - pos[j * 3 + 1];
    w[2] = pos[nd * 3 + 2] - pos[j * 3 + 2];
    w[3] = __int_as_float(j << 8);          // byte offset of packed-KV row
    *(float4v*)&sEdge[nl * 260 + p * 4] = w;
  }
  __syncthreads();

  const int lane = threadIdx.x;
  const int g    = lane >> 4;
  const int cl   = lane & 15;
  const int nodeA = node0 + g;
  const int nodeB = node0 + 4 + g;
  const unsigned clOfs = (unsigned)(cl << 4);

  float4v wp0, wp1, wp2, bpv, bqA, bqB;
  {
    const float* WpD = Wp + dd * 192;
    wp0 = *(const float4v*)(WpD + 0 * 64 + cl * 4) * L2E;
    wp1 = *(const float4v*)(WpD + 1 * 64 + cl * 4) * L2E;
    wp2 = *(const float4v*)(WpD + 2 * 64 + cl * 4) * L2E;
    bpv = *(const float4v*)(bp + dd * 64 + cl * 4) * L2E;
    ushort4v qA = *(const ushort4v*)(qbf + ((size_t)dd * NP + nodeA) * CH + cl * 4);
    ushort4v qB = *(const ushort4v*)(qbf + ((size_t)dd * NP + nodeB) * CH + cl * 4);
#pragma unroll
    for (int i = 0; i < 4; ++i) {
      bqA[i] = b2f(qA[i]) + bpv[i];
      bqB[i] = b2f(qB[i]) + bpv[i];
    }
  }
  const char* KVb = (const char*)(kvp + (size_t)dd * NP * CH);

  const int e0   = (half * 8) << dd;        // starting edge slot
  const int estp = (1 << dd) * 4;           // floats per edge step
  const float* epA = &sEdge[g * 260] + e0 * 4;
  const float* epB = &sEdge[(4 + g) * 260] + e0 * 4;

  float4v sA = {0.f, 0.f, 0.f, 0.f}, accA = {0.f, 0.f, 0.f, 0.f};
  float4v sB = {0.f, 0.f, 0.f, 0.f}, accB = {0.f, 0.f, 0.f, 0.f};
#pragma unroll
  for (int e = 0; e < 8; ++e) {
    float4v wA = *(const float4v*)(epA + e * estp);
    float4v wB = *(const float4v*)(epB + e * estp);
    uint4v uA = *(const uint4v*)(KVb + (__float_as_uint(wA[3]) + clOfs));
    uint4v uB = *(const uint4v*)(KVb + (__float_as_uint(wB[3]) + clOfs));
    float4v tA = bqA + wA[0] * wp0 + wA[1] * wp1 + wA[2] * wp2;
    float4v tB = bqB + wB[0] * wp0 + wB[1] * wp1 + wB[2] * wp2;
    float4v gA, gB;
#pragma unroll
    for (int i = 0; i < 4; ++i) {
      // unmasked K: low 16 bits are V's bits -> <=0.78% perturbation (~bf16 ulp)
      gA[i] = __builtin_amdgcn_exp2f(tA[i] - __uint_as_float(uA[i]));
      gB[i] = __builtin_amdgcn_exp2f(tB[i] - __uint_as_float(uB[i]));
    }
    float4v vA, vB;
#pragma unroll
    for (int i = 0; i < 4; ++i) {
      vA[i] = __uint_as_float(uA[i] << 16);
      vB[i] = __uint_as_float(uB[i] << 16);
    }
    sA += gA;  accA += gA * (vA + tA * LN2);
    sB += gB;  accB += gB * (vB + tB * LN2);
  }

  // publish partials: P = accv - q*s  (q = (bq - bp_s)*ln2, uniform per node)
  {
    float4v qoA, qoB;
#pragma unroll
    for (int i = 0; i < 4; ++i) {
      qoA[i] = (bqA[i] - bpv[i]) * LN2;
      qoB[i] = (bqB[i] - bpv[i]) * LN2;
    }
    *(float4v*)&sS[(wy * 8 + g) * 68 + cl * 4]     = sA;
    *(float4v*)&sP[(wy * 8 + g) * 68 + cl * 4]     = accA - qoA * sA;
    *(float4v*)&sS[(wy * 8 + 4 + g) * 68 + cl * 4] = sB;
    *(float4v*)&sP[(wy * 8 + 4 + g) * 68 + cl * 4] = accB - qoB * sB;
  }
  __syncthreads();

  if (wy < 2) {                             // two combine waves (nodes A / B)
    const int g2 = wy * 4 + g;
    const int node = node0 + g2;
    float4v res;
#pragma unroll
    for (int d2 = 0; d2 < 3; ++d2) {
      float4v s0 = *(const float4v*)&sS[((d2    ) * 8 + g2) * 68 + cl * 4];
      float4v s1 = *(const float4v*)&sS[((d2 + 3) * 8 + g2) * 68 + cl * 4];
      float4v p0 = *(const float4v*)&sP[((d2    ) * 8 + g2) * 68 + cl * 4];
      float4v p1 = *(const float4v*)&sP[((d2 + 3) * 8 + g2) * 68 + cl * 4];
      float4v st = s0 + s1;
      float4v pt = p0 + p1;
      float4v r;
#pragma unroll
      for (int i = 0; i < 4; ++i)
        r[i] = pt[i] * __builtin_amdgcn_rcpf(st[i] + EPSF);
      if (d2 == 0) res = r;
      else {
#pragma unroll
        for (int i = 0; i < 4; ++i) res[i] = fmaxf(res[i], r[i]);
      }
    }
    const int b = node / PTS;
    const float* pp = poolP + (size_t)(b * PPB) * CH + cl * 4;
    float4v pv = *(const float4v*)pp;
#pragma unroll
    for (int q2 = 1; q2 < PPB; ++q2) {
      float4v t2 = *(const float4v*)(pp + (size_t)q2 * CH);
#pragma unroll
      for (int i = 0; i < 4; ++i) pv[i] = fmaxf(pv[i], t2[i]);
    }
    float4v xv = *(const float4v*)(x + (size_t)node * CH + cl * 4);
#pragma unroll
    for (int i = 0; i < 4; ++i) res[i] = fmaxf(res[i], pv[i]) + xv[i];
    *(float4v*)(out + (size_t)node * CH + cl * 4) = res;
  }
}

// ---------------------------------------------------------------------------
extern "C" void kernel_launch(void* const* d_in, const int* in_sizes, int n_in,
                              void* d_out, int out_size, void* d_ws, size_t ws_size,
                              hipStream_t stream) {
  const float* x    = (const float*)d_in[0];
  const float* pos  = (const float*)d_in[1];
  const float* Wv   = (const float*)d_in[2];
  const float* Wq   = (const float*)d_in[3];
  const float* Wk   = (const float*)d_in[4];
  const float* Wp   = (const float*)d_in[5];
  const float* bp   = (const float*)d_in[6];
  const int*   ei   = (const int*)d_in[7];
  float* out = (float*)d_out;

  char* wsb = (char*)d_ws;
  ushort* qbf   = (ushort*)wsb;
  unsigned int* kvp = (unsigned int*)(wsb + QBF_BYTES);
  ushort* x_bf  = (ushort*)(wsb + QBF_BYTES + KVP_BYTES);
  ushort* wpack = (ushort*)(wsb + QBF_BYTES + KVP_BYTES + XBF_BYTES);
  float*  poolP = (float*)(wsb + QBF_BYTES + KVP_BYTES + XBF_BYTES +
                           (size_t)WPACK_ELEMS * 2);

  // 0) pool partials + convert + pack
  {
    int convBlocks = (XV + WPACK_ELEMS + 255) / 256;
    dim3 grid(NB * PPB + convBlocks);
    hipLaunchKernelGGL(prep_kernel, grid, dim3(256), 0, stream,
                       x, Wv, Wq, Wk, x_bf, wpack, poolP);
  }
  // 1) Q + packed KV via MFMA (6 slices, 1 tile/wave)
  {
    dim3 grid((NTILES + 3) / 4, 6);
    dim3 block(64, 4);
    hipLaunchKernelGGL(qkv_mfma, grid, block, 0, stream, x_bf, wpack, qbf, kvp);
  }
  // 2) fused attention + combine (8 nodes/block, 2 streams/wave)
  {
    dim3 grid(8 * ((OCTS + 7) / 8));
    dim3 block(64, 6);
    hipLaunchKernelGGL(attn_kernel, grid, block, 0, stream,
                       x, pos, Wp, bp, ei, qbf, kvp, poolP, out);
  }
}

// Round 8
// 198.300 us; speedup vs baseline: 3.2249x; 3.2249x over previous
//
#include <hip/hip_runtime.h>
#include <math.h>

#define NP 50000
#define CH 64
#define KMAX 64
#define KNN 16
#define NB 25
#define PTS (NP / NB)            // 2000
#define EPSF 1e-16f
#define NTILES (NP / 16)         // 3125 (16-node tiles for qkv)
#define OCTS (NP / 8)            // 6250 (8-node octets for attn)
#define L2E 1.4426950408889634f
#define LN2 0.6931471805599453f
#define PPB 8                    // pool partials per cloud
#define PROWS (PTS / PPB)        // 250

typedef __attribute__((ext_vector_type(8))) short short8;
typedef __attribute__((ext_vector_type(4))) float float4v;
typedef __attribute__((ext_vector_type(4))) unsigned int uint4v;
typedef __attribute__((ext_vector_type(2))) unsigned int uint2v;
typedef __attribute__((ext_vector_type(4))) unsigned short ushort4v;

__device__ __forceinline__ ushort f2b(float f) {
  unsigned u = __float_as_uint(f);
  unsigned r = (u + 0x7FFFu + ((u >> 16) & 1u)) >> 16;
  return (ushort)r;
}
__device__ __forceinline__ float b2f(ushort h) {
  return __uint_as_float(((unsigned)h) << 16);
}

// ws layout (bytes):
//   qbf  : 3 * NP * CH * 2   (bf16, log2e-scaled Q)
//   kvp  : 3 * NP * CH * 4   (packed dword: K_s bf16 hi | V bf16 lo)
//   x_bf : NP * CH * 2
//   wpack: 36864 ushort (A-frag layout; Q,K pre-scaled by log2e)
//   poolP: NB * PPB * CH fp32 (per-cloud pool partials)
#define QBF_BYTES   ((size_t)3 * NP * CH * 2)
#define KVP_BYTES   ((size_t)3 * NP * CH * 4)
#define XBF_BYTES   ((size_t)NP * CH * 2)
#define WPACK_ELEMS (9 * 4 * 2 * 64 * 8)
#define XV (NP * CH / 4)

// ---------------------------------------------------------------------------
// Kernel 0: prep = pool partials (blocks 0..NB*PPB-1) + x->bf16 + W pack.
// ---------------------------------------------------------------------------
__global__ __launch_bounds__(256) void prep_kernel(
    const float* __restrict__ x,
    const float* __restrict__ Wv,
    const float* __restrict__ Wq,
    const float* __restrict__ Wk,
    ushort* __restrict__ x_bf,
    ushort* __restrict__ wpack,
    float* __restrict__ poolP) {
  const int tid = threadIdx.x;
  const int bid = blockIdx.x;
  __shared__ float red[4][CH];

  if (bid < NB * PPB) {                 // ---- pool partial path ----
    const int lane = tid & 63;
    const int wave = tid >> 6;
    const int cloud = bid >> 3;
    const int part  = bid & 7;
    const float* xb = x + ((size_t)cloud * PTS + part * PROWS) * CH;
    float m0 = -INFINITY, m1 = -INFINITY;
    for (int r = wave * 2; r < PROWS; r += 8) {
      m0 = fmaxf(m0, xb[(size_t)(r + 0) * CH + lane]);
      m1 = fmaxf(m1, xb[(size_t)(r + 1) * CH + lane]);
    }
    red[wave][lane] = fmaxf(m0, m1);
    __syncthreads();
    if (wave == 0) {
      poolP[(size_t)bid * CH + lane] = fmaxf(fmaxf(red[0][lane], red[1][lane]),
                                             fmaxf(red[2][lane], red[3][lane]));
    }
  } else {                              // ---- convert / pack path ----
    const int gid = (bid - NB * PPB) * 256 + tid;
    if (gid < XV) {
      const float4* xv = (const float4*)x;
      float4 v = xv[gid];
      ushort4v o;
      o[0] = f2b(v.x); o[1] = f2b(v.y); o[2] = f2b(v.z); o[3] = f2b(v.w);
      *(ushort4v*)(x_bf + (size_t)gid * 4) = o;
    } else {
      int pid = gid - XV;
      if (pid < WPACK_ELEMS) {
        int j     = pid & 7;
        int lane  = (pid >> 3) & 63;
        int kstep = (pid >> 9) & 1;
        int mtile = (pid >> 10) & 3;
        int mat   = pid >> 12;
        const float* W;
        int d;
        float scale;
        if (mat < 3)      { W = Wq; d = mat;     scale = L2E; }
        else if (mat < 6) { W = Wk; d = mat - 3; scale = L2E; }
        else              { W = Wv; d = mat - 6; scale = 1.f; }
        int oc = mtile * 16 + (lane & 15);
        int ic = kstep * 32 + ((lane >> 4) & 3) * 8 + j;
        wpack[pid] = f2b(W[d * CH * CH + ic * CH + oc] * scale);
      }
    }
  }
}

// ---------------------------------------------------------------------------
// Kernel 1: projections via MFMA 16x16x32 bf16 (A=W^T, B=x^T). 1 tile/wave.
// grid.y: 0..2 = Q_dd (8 A-frags), 3..5 = KV_dd packed (16 A-frags).
// D lane: node=lane&15, oc=mt*16+(lane>>4)*4+reg.
// ---------------------------------------------------------------------------
__global__ __launch_bounds__(256) void qkv_mfma(
    const ushort* __restrict__ x_bf,
    const ushort* __restrict__ wpack,
    ushort* __restrict__ qbf,
    unsigned int* __restrict__ kvp) {
  const int lane = threadIdx.x;
  const int tile = blockIdx.x * 4 + threadIdx.y;
  if (tile >= NTILES) return;
  const int y = blockIdx.y;
  const int kbase = (lane >> 4) * 8;
  const int myNode = tile * 16 + (lane & 15);
  const ushort* xr = x_bf + (size_t)myNode * CH;
  short8 b0 = *(const short8*)(xr + kbase);
  short8 b1 = *(const short8*)(xr + 32 + kbase);

  if (y < 3) {                             // ---- Q slice ----
    const int dd = y;
    ushort* outQ = qbf + (size_t)dd * NP * CH;
#pragma unroll
    for (int mt = 0; mt < 4; ++mt) {
      short8 a0 = *(const short8*)(wpack +
          ((((size_t)dd * 4 + mt) * 2 + 0) * 64 + lane) * 8);
      short8 a1 = *(const short8*)(wpack +
          ((((size_t)dd * 4 + mt) * 2 + 1) * 64 + lane) * 8);
      float4v acc = {0.f, 0.f, 0.f, 0.f};
      acc = __builtin_amdgcn_mfma_f32_16x16x32_bf16(a0, b0, acc, 0, 0, 0);
      acc = __builtin_amdgcn_mfma_f32_16x16x32_bf16(a1, b1, acc, 0, 0, 0);
      int oc = mt * 16 + (lane >> 4) * 4;
      uint2v o;
      o[0] = (unsigned)f2b(acc[0]) | ((unsigned)f2b(acc[1]) << 16);
      o[1] = (unsigned)f2b(acc[2]) | ((unsigned)f2b(acc[3]) << 16);
      *(uint2v*)(outQ + (size_t)myNode * CH + oc) = o;
    }
  } else {                                 // ---- KV packed slice ----
    const int dd = y - 3;
    unsigned int* outKV = kvp + (size_t)dd * NP * CH;
#pragma unroll
    for (int mt = 0; mt < 4; ++mt) {
      short8 k0 = *(const short8*)(wpack +
          ((((size_t)(3 + dd) * 4 + mt) * 2 + 0) * 64 + lane) * 8);
      short8 k1 = *(const short8*)(wpack +
          ((((size_t)(3 + dd) * 4 + mt) * 2 + 1) * 64 + lane) * 8);
      short8 v0 = *(const short8*)(wpack +
          ((((size_t)(6 + dd) * 4 + mt) * 2 + 0) * 64 + lane) * 8);
      short8 v1 = *(const short8*)(wpack +
          ((((size_t)(6 + dd) * 4 + mt) * 2 + 1) * 64 + lane) * 8);
      float4v aK = {0.f, 0.f, 0.f, 0.f};
      float4v aV = {0.f, 0.f, 0.f, 0.f};
      aK = __builtin_amdgcn_mfma_f32_16x16x32_bf16(k0, b0, aK, 0, 0, 0);
      aK = __builtin_amdgcn_mfma_f32_16x16x32_bf16(k1, b1, aK, 0, 0, 0);
      aV = __builtin_amdgcn_mfma_f32_16x16x32_bf16(v0, b0, aV, 0, 0, 0);
      aV = __builtin_amdgcn_mfma_f32_16x16x32_bf16(v1, b1, aV, 0, 0, 0);
      int oc = mt * 16 + (lane >> 4) * 4;
      uint4v o;
#pragma unroll
      for (int i = 0; i < 4; ++i)
        o[i] = ((unsigned)f2b(aK[i]) << 16) | (unsigned)f2b(aV[i]);
      *(uint4v*)(outKV + (size_t)myNode * CH + oc) = o;
    }
  }
}

// ---------------------------------------------------------------------------
// Kernel 2: fused attention. Block = (64,6): 8 nodes; wave wy = (dd, half)
// processes TWO independent node groups A (0-3) and B (4-7) interleaved
// (2 dependence streams, setup amortized 2x). Partials {s, P=accv-q*s} via
// padded LDS; waves 0/1 combine nodes A/B in parallel.
// __launch_bounds__(384, 4): <=128 VGPRs -- the (384,6) variant capped at
// ~85 VGPRs and spilled the 2-stream loop to scratch (1.3 GB writes, r7).
// ---------------------------------------------------------------------------
__global__ __launch_bounds__(384, 4) void attn_kernel(
    const float* __restrict__ x,
    const float* __restrict__ pos,
    const float* __restrict__ Wp,
    const float* __restrict__ bp,
    const int*   __restrict__ edge_src,
    const ushort* __restrict__ qbf,
    const unsigned int* __restrict__ kvp,
    const float* __restrict__ poolP,
    float* __restrict__ out) {
  const int bx  = blockIdx.x;
  const int xcd = bx & 7;
  const int kk  = bx >> 3;
  const int base = (OCTS * xcd) >> 3;
  const int cnt  = ((OCTS * (xcd + 1)) >> 3) - base;
  if (kk >= cnt) return;                    // whole-block uniform
  const int node0 = (base + kk) * 8;

  const int wy   = threadIdx.y;             // 0..5
  const int dd   = wy % 3;                  // wave-uniform dilation
  const int half = wy / 3;                  // 0 or 1 (edge half)
  const int tid  = wy * 64 + threadIdx.x;

  __shared__ float sEdge[8 * 260];          // [nl][p] {relx,rely,relz,rowOfs}
  __shared__ float sS[6 * 8 * 68];          // [wy][nl][ch] partial s
  __shared__ float sP[6 * 8 * 68];          // [wy][nl][ch] partial accv-q*s

  for (int r = tid; r < 8 * KMAX; r += 384) {
    int nl = r >> 6, p = r & 63;
    int nd = node0 + nl;
    int j = edge_src[(size_t)nd * KMAX + p];
    float4v w;
    w[0] = pos[nd * 3 + 0] - pos[j * 3 + 0];
    w[1] = pos[nd * 3 + 1] - pos[j * 3 + 1];
    w[2] = pos[nd * 3 + 2] - pos[j * 3 + 2];
    w[3] = __int_as_float(j << 8);          // byte offset of packed-KV row
    *(float4v*)&sEdge[nl * 260 + p * 4] = w;
  }
  __syncthreads();

  const int lane = threadIdx.x;
  const int g    = lane >> 4;
  const int cl   = lane & 15;
  const int nodeA = node0 + g;
  const int nodeB = node0 + 4 + g;
  const unsigned clOfs = (unsigned)(cl << 4);

  float4v wp0, wp1, wp2, bpv, bqA, bqB;
  {
    const float* WpD = Wp + dd * 192;
    wp0 = *(const float4v*)(WpD + 0 * 64 + cl * 4) * L2E;
    wp1 = *(const float4v*)(WpD + 1 * 64 + cl * 4) * L2E;
    wp2 = *(const float4v*)(WpD + 2 * 64 + cl * 4) * L2E;
    bpv = *(const float4v*)(bp + dd * 64 + cl * 4) * L2E;
    ushort4v qA = *(const ushort4v*)(qbf + ((size_t)dd * NP + nodeA) * CH + cl * 4);
    ushort4v qB = *(const ushort4v*)(qbf + ((size_t)dd * NP + nodeB) * CH + cl * 4);
#pragma unroll
    for (int i = 0; i < 4; ++i) {
      bqA[i] = b2f(qA[i]) + bpv[i];
      bqB[i] = b2f(qB[i]) + bpv[i];
    }
  }
  const char* KVb = (const char*)(kvp + (size_t)dd * NP * CH);

  const int e0   = (half * 8) << dd;        // starting edge slot
  const int estp = (1 << dd) * 4;           // floats per edge step
  const float* epA = &sEdge[g * 260] + e0 * 4;
  const float* epB = &sEdge[(4 + g) * 260] + e0 * 4;

  float4v sA = {0.f, 0.f, 0.f, 0.f}, accA = {0.f, 0.f, 0.f, 0.f};
  float4v sB = {0.f, 0.f, 0.f, 0.f}, accB = {0.f, 0.f, 0.f, 0.f};
#pragma unroll
  for (int e = 0; e < 8; ++e) {
    float4v wA = *(const float4v*)(epA + e * estp);
    float4v wB = *(const float4v*)(epB + e * estp);
    uint4v uA = *(const uint4v*)(KVb + (__float_as_uint(wA[3]) + clOfs));
    uint4v uB = *(const uint4v*)(KVb + (__float_as_uint(wB[3]) + clOfs));
    float4v tA = bqA + wA[0] * wp0 + wA[1] * wp1 + wA[2] * wp2;
    float4v tB = bqB + wB[0] * wp0 + wB[1] * wp1 + wB[2] * wp2;
    float4v gA, gB;
#pragma unroll
    for (int i = 0; i < 4; ++i) {
      // unmasked K: low 16 bits are V's bits -> <=0.78% perturbation (~bf16 ulp)
      gA[i] = __builtin_amdgcn_exp2f(tA[i] - __uint_as_float(uA[i]));
      gB[i] = __builtin_amdgcn_exp2f(tB[i] - __uint_as_float(uB[i]));
    }
    float4v vA, vB;
#pragma unroll
    for (int i = 0; i < 4; ++i) {
      vA[i] = __uint_as_float(uA[i] << 16);
      vB[i] = __uint_as_float(uB[i] << 16);
    }
    sA += gA;  accA += gA * (vA + tA * LN2);
    sB += gB;  accB += gB * (vB + tB * LN2);
  }

  // publish partials: P = accv - q*s  (q = (bq - bp_s)*ln2, uniform per node)
  {
    float4v qoA, qoB;
#pragma unroll
    for (int i = 0; i < 4; ++i) {
      qoA[i] = (bqA[i] - bpv[i]) * LN2;
      qoB[i] = (bqB[i] - bpv[i]) * LN2;
    }
    *(float4v*)&sS[(wy * 8 + g) * 68 + cl * 4]     = sA;
    *(float4v*)&sP[(wy * 8 + g) * 68 + cl * 4]     = accA - qoA * sA;
    *(float4v*)&sS[(wy * 8 + 4 + g) * 68 + cl * 4] = sB;
    *(float4v*)&sP[(wy * 8 + 4 + g) * 68 + cl * 4] = accB - qoB * sB;
  }
  __syncthreads();

  if (wy < 2) {                             // two combine waves (nodes A / B)
    const int g2 = wy * 4 + g;
    const int node = node0 + g2;
    float4v res;
#pragma unroll
    for (int d2 = 0; d2 < 3; ++d2) {
      float4v s0 = *(const float4v*)&sS[((d2    ) * 8 + g2) * 68 + cl * 4];
      float4v s1 = *(const float4v*)&sS[((d2 + 3) * 8 + g2) * 68 + cl * 4];
      float4v p0 = *(const float4v*)&sP[((d2    ) * 8 + g2) * 68 + cl * 4];
      float4v p1 = *(const float4v*)&sP[((d2 + 3) * 8 + g2) * 68 + cl * 4];
      float4v st = s0 + s1;
      float4v pt = p0 + p1;
      float4v r;
#pragma unroll
      for (int i = 0; i < 4; ++i)
        r[i] = pt[i] * __builtin_amdgcn_rcpf(st[i] + EPSF);
      if (d2 == 0) res = r;
      else {
#pragma unroll
        for (int i = 0; i < 4; ++i) res[i] = fmaxf(res[i], r[i]);
      }
    }
    const int b = node / PTS;
    const float* pp = poolP + (size_t)(b * PPB) * CH + cl * 4;
    float4v pv = *(const float4v*)pp;
#pragma unroll
    for (int q2 = 1; q2 < PPB; ++q2) {
      float4v t2 = *(const float4v*)(pp + (size_t)q2 * CH);
#pragma unroll
      for (int i = 0; i < 4; ++i) pv[i] = fmaxf(pv[i], t2[i]);
    }
    float4v xv = *(const float4v*)(x + (size_t)node * CH + cl * 4);
#pragma unroll
    for (int i = 0; i < 4; ++i) res[i] = fmaxf(res[i], pv[i]) + xv[i];
    *(float4v*)(out + (size_t)node * CH + cl * 4) = res;
  }
}

// ---------------------------------------------------------------------------
extern "C" void kernel_launch(void* const* d_in, const int* in_sizes, int n_in,
                              void* d_out, int out_size, void* d_ws, size_t ws_size,
                              hipStream_t stream) {
  const float* x    = (const float*)d_in[0];
  const float* pos  = (const float*)d_in[1];
  const float* Wv   = (const float*)d_in[2];
  const float* Wq   = (const float*)d_in[3];
  const float* Wk   = (const float*)d_in[4];
  const float* Wp   = (const float*)d_in[5];
  const float* bp   = (const float*)d_in[6];
  const int*   ei   = (const int*)d_in[7];
  float* out = (float*)d_out;

  char* wsb = (char*)d_ws;
  ushort* qbf   = (ushort*)wsb;
  unsigned int* kvp = (unsigned int*)(wsb + QBF_BYTES);
  ushort* x_bf  = (ushort*)(wsb + QBF_BYTES + KVP_BYTES);
  ushort* wpack = (ushort*)(wsb + QBF_BYTES + KVP_BYTES + XBF_BYTES);
  float*  poolP = (float*)(wsb + QBF_BYTES + KVP_BYTES + XBF_BYTES +
                           (size_t)WPACK_ELEMS * 2);

  // 0) pool partials + convert + pack
  {
    int convBlocks = (XV + WPACK_ELEMS + 255) / 256;
    dim3 grid(NB * PPB + convBlocks);
    hipLaunchKernelGGL(prep_kernel, grid, dim3(256), 0, stream,
                       x, Wv, Wq, Wk, x_bf, wpack, poolP);
  }
  // 1) Q + packed KV via MFMA (6 slices, 1 tile/wave)
  {
    dim3 grid((NTILES + 3) / 4, 6);
    dim3 block(64, 4);
    hipLaunchKernelGGL(qkv_mfma, grid, block, 0, stream, x_bf, wpack, qbf, kvp);
  }
  // 2) fused attention + combine (8 nodes/block, 2 streams/wave)
  {
    dim3 grid(8 * ((OCTS + 7) / 8));
    dim3 block(64, 6);
    hipLaunchKernelGGL(attn_kernel, grid, block, 0, stream,
                       x, pos, Wp, bp, ei, qbf, kvp, poolP, out);
  }
}